// Round 1
// baseline (1085.447 us; speedup 1.0000x reference)
//
#include <hip/hip_runtime.h>
#include <hip/hip_bf16.h>
#include <cmath>

typedef __bf16 bf16x8 __attribute__((ext_vector_type(8)));
typedef __bf16 bf16x4 __attribute__((ext_vector_type(4)));
typedef float f32x4 __attribute__((ext_vector_type(4)));

// ---------------------------------------------------------------------------
// SEQ_idxes may be int64 (reference says .astype(jnp.int64)) or int32 (JAX
// x64-disabled). Detect: as int32 words, int64 layout = [f0_lo, f0_hi(=0), ...]
// while int32 layout = [f0, s0(>=2049), ...]. So seq[1]==0 <=> int64.
__device__ inline int get_first(const int* __restrict__ seq, int b) {
    int stride = (seq[1] == 0) ? 4 : 2;
    return seq[b * stride];
}

// ---------------------------------------------------------------------------
__global__ __launch_bounds__(256) void cast_f32_bf16(const float* __restrict__ in,
                                                     __bf16* __restrict__ out, int n4) {
    int i = blockIdx.x * 256 + threadIdx.x;
    if (i >= n4) return;
    float4 v = ((const float4*)in)[i];
    bf16x4 o;
    o[0] = (__bf16)v.x; o[1] = (__bf16)v.y; o[2] = (__bf16)v.z; o[3] = (__bf16)v.w;
    ((bf16x4*)out)[i] = o;
}

// ---------------------------------------------------------------------------
// gemm_bt: C[m][n] = sum_k A[m][k] * Bt[n][k]  (+ bias[n])
// A: row-major M x K (lda), Bt: row-major N x K (ldb).
// 128x128 tile, BK=64, 256 threads = 4 waves (2x2), each wave 64x64 via
// 4x4 grid of 16x16x32 bf16 MFMA tiles.
// EPI: 0 = bf16 store + bias, 1 = bf16 TRANSPOSED store (C[n][m]) + bias,
//      2 = bf16 store no bias, 3 = fp32 store no bias.
// exit_mode: 0 none, 1 skip if m0>=first, 2 skip if n0>=first.
// k_mode: 0 K=Kfix, 1 K=ceil(first/64)*64.
template <int EPI>
__global__ __launch_bounds__(256) void gemm_bt(
    const __bf16* __restrict__ A, int lda, long strideA,
    const __bf16* __restrict__ B, int ldb, long strideB,
    const float* __restrict__ bias,
    void* __restrict__ Cv, int ldc, long strideC,
    int Kfix, const int* __restrict__ seq, int exit_mode, int k_mode) {
    int z = blockIdx.z;
    int m0 = blockIdx.x * 128, n0 = blockIdx.y * 128;
    int first = 0;
    if (seq) first = get_first(seq, z);
    if (exit_mode == 1 && m0 >= first) return;
    if (exit_mode == 2 && n0 >= first) return;
    int K = (k_mode == 1) ? (((first + 63) >> 6) << 6) : Kfix;

    A += z * strideA;
    B += z * strideB;

    // +8 bf16 pad -> row stride 144 B = 36 dwords: ds_read_b128 frag reads are
    // 2-way bank aliased only (free per m136).
    __shared__ __bf16 As[128][72];
    __shared__ __bf16 Bs[128][72];

    int tid = threadIdx.x;
    int lane = tid & 63, wid = tid >> 6;
    int waveM = (wid & 1) * 64, waveN = (wid >> 1) * 64;
    int quad = lane >> 4, l16 = lane & 15;

    f32x4 acc[4][4] = {};

    int srow = tid >> 3;        // 0..31, 8 threads per 64-col row (16B each)
    int scol = (tid & 7) * 8;   // 0..56
    const __bf16* Ag = A + (long)(m0 + srow) * lda + scol;
    const __bf16* Bg = B + (long)(n0 + srow) * ldb + scol;

    for (int k0 = 0; k0 < K; k0 += 64) {
        int4 av[4], bv[4];
#pragma unroll
        for (int p = 0; p < 4; ++p) {
            av[p] = *(const int4*)(Ag + (long)(p * 32) * lda + k0);
            bv[p] = *(const int4*)(Bg + (long)(p * 32) * ldb + k0);
        }
        __syncthreads();  // previous iter's ds_reads done before overwrite
#pragma unroll
        for (int p = 0; p < 4; ++p) {
            *(int4*)&As[srow + p * 32][scol] = av[p];
            *(int4*)&Bs[srow + p * 32][scol] = bv[p];
        }
        __syncthreads();
#pragma unroll
        for (int s = 0; s < 2; ++s) {
            bf16x8 af[4], bfr[4];
#pragma unroll
            for (int i = 0; i < 4; ++i) {
                af[i]  = *(const bf16x8*)&As[waveM + i * 16 + l16][s * 32 + quad * 8];
                bfr[i] = *(const bf16x8*)&Bs[waveN + i * 16 + l16][s * 32 + quad * 8];
            }
#pragma unroll
            for (int i = 0; i < 4; ++i)
#pragma unroll
                for (int j = 0; j < 4; ++j)
                    acc[i][j] = __builtin_amdgcn_mfma_f32_16x16x32_bf16(af[i], bfr[j], acc[i][j], 0, 0, 0);
        }
    }

    // Epilogue. C/D frag: col = l16 (n), row = quad*4 + reg (m). [m89-verified]
    if (EPI == 0 || EPI == 2) {
        __bf16* C = (__bf16*)Cv + z * strideC;
#pragma unroll
        for (int i = 0; i < 4; ++i) {
            int rowb = m0 + waveM + i * 16 + quad * 4;
#pragma unroll
            for (int j = 0; j < 4; ++j) {
                int col = n0 + waveN + j * 16 + l16;
                float bv_ = (EPI == 0) ? bias[col] : 0.0f;
#pragma unroll
                for (int r = 0; r < 4; ++r)
                    C[(long)(rowb + r) * ldc + col] = (__bf16)(acc[i][j][r] + bv_);
            }
        }
    } else if (EPI == 1) {
        __bf16* C = (__bf16*)Cv + z * strideC;
#pragma unroll
        for (int i = 0; i < 4; ++i) {
            int rowb = m0 + waveM + i * 16 + quad * 4;
#pragma unroll
            for (int j = 0; j < 4; ++j) {
                int col = n0 + waveN + j * 16 + l16;
                float bv_ = bias[col];
                bf16x4 o;
#pragma unroll
                for (int r = 0; r < 4; ++r) o[r] = (__bf16)(acc[i][j][r] + bv_);
                *(bf16x4*)&C[(long)col * ldc + rowb] = o;  // rowb % 4 == 0 -> 8B aligned
            }
        }
    } else {
        float* C = (float*)Cv + z * strideC;
#pragma unroll
        for (int i = 0; i < 4; ++i) {
            int rowb = m0 + waveM + i * 16 + quad * 4;
#pragma unroll
            for (int j = 0; j < 4; ++j) {
                int col = n0 + waveN + j * 16 + l16;
#pragma unroll
                for (int r = 0; r < 4; ++r)
                    C[(long)(rowb + r) * ldc + col] = acc[i][j][r];
            }
        }
    }
}

// ---------------------------------------------------------------------------
// Row softmax over k in [1, first), in-place on bf16 scores -> probs.
// One wave per row (4 rows / 256-thread block). 3 read passes (row is 4KB,
// L1-resident). Zero-fills k=0 and [first, roundup128(first)).
__global__ __launch_bounds__(256) void softmax_rows(__bf16* __restrict__ S,
                                                    const int* __restrict__ seq,
                                                    float scale) {
    int b = blockIdx.y;
    int q = blockIdx.x * 4 + (threadIdx.x >> 6);
    int lane = threadIdx.x & 63;
    int first = get_first(seq, b);
    __bf16* row = S + ((long)b * 4096 + q) * 2048;

    float m = -INFINITY;
    for (int k = 1 + lane; k < first; k += 64) m = fmaxf(m, (float)row[k]);
#pragma unroll
    for (int off = 32; off; off >>= 1) m = fmaxf(m, __shfl_xor(m, off));

    float l = 0.0f;
    for (int k = 1 + lane; k < first; k += 64) l += __expf(scale * ((float)row[k] - m));
#pragma unroll
    for (int off = 32; off; off >>= 1) l += __shfl_xor(l, off);
    float inv = 1.0f / l;

    for (int k = 1 + lane; k < first; k += 64)
        row[k] = (__bf16)(__expf(scale * ((float)row[k] - m)) * inv);

    if (lane == 0) row[0] = (__bf16)0.0f;
    int kend = (first + 127) & ~127;
    for (int k = first + lane; k < kend; k += 64) row[k] = (__bf16)0.0f;
}

// ---------------------------------------------------------------------------
extern "C" void kernel_launch(void* const* d_in, const int* in_sizes, int n_in,
                              void* d_out, int out_size, void* d_ws, size_t ws_size,
                              hipStream_t stream) {
    const int B = 8, S = 4096, E = 768, SK = 2048;
    const float* ebd  = (const float*)d_in[0];
    const int*   seq  = (const int*)d_in[1];
    const float* Wq_w = (const float*)d_in[2];
    const float* Wq_b = (const float*)d_in[3];
    const float* Wk_w = (const float*)d_in[4];
    const float* Wk_b = (const float*)d_in[5];
    const float* Wv_w = (const float*)d_in[6];
    const float* Wv_b = (const float*)d_in[7];
    float* out = (float*)d_out;

    char* p = (char*)d_ws;
    __bf16* ebd_bf = (__bf16*)p; p += (size_t)B * S * E * 2;   // 50.3 MB
    __bf16* wq = (__bf16*)p;     p += (size_t)E * E * 2;
    __bf16* wk = (__bf16*)p;     p += (size_t)E * E * 2;
    __bf16* wv = (__bf16*)p;     p += (size_t)E * E * 2;
    __bf16* Qb = (__bf16*)p;     p += (size_t)B * S * E * 2;   // 50.3 MB
    __bf16* Kb = (__bf16*)p;     p += (size_t)B * SK * E * 2;  // 25.2 MB
    __bf16* VT = (__bf16*)p;     p += (size_t)B * E * SK * 2;  // 25.2 MB (V^T: [b][e][k])
    __bf16* Sb = (__bf16*)p;     p += (size_t)B * S * SK * 2;  // 134.2 MB

    // casts
    cast_f32_bf16<<<(B * S * E / 4 + 255) / 256, 256, 0, stream>>>(ebd, ebd_bf, B * S * E / 4);
    cast_f32_bf16<<<(E * E / 4 + 255) / 256, 256, 0, stream>>>(Wq_w, wq, E * E / 4);
    cast_f32_bf16<<<(E * E / 4 + 255) / 256, 256, 0, stream>>>(Wk_w, wk, E * E / 4);
    cast_f32_bf16<<<(E * E / 4 + 255) / 256, 256, 0, stream>>>(Wv_w, wv, E * E / 4);

    // Q = ebd @ Wq^T + bq   (M = B*S as one GEMM)
    gemm_bt<0><<<dim3(B * S / 128, E / 128, 1), 256, 0, stream>>>(
        ebd_bf, E, 0, wq, E, 0, Wq_b, Qb, E, 0, E, nullptr, 0, 0);
    // K[b] = ebd[b,0:2048] @ Wk^T + bk   (early-exit m-tiles >= first)
    gemm_bt<0><<<dim3(SK / 128, E / 128, B), 256, 0, stream>>>(
        ebd_bf, E, (long)S * E, wk, E, 0, Wk_b, Kb, E, (long)SK * E, E, seq, 1, 0);
    // VT[b] = (ebd[b,0:2048] @ Wv^T + bv)^T  (transposed store)
    gemm_bt<1><<<dim3(SK / 128, E / 128, B), 256, 0, stream>>>(
        ebd_bf, E, (long)S * E, wv, E, 0, Wv_b, VT, SK, (long)E * SK, E, seq, 1, 0);
    // scores[b] = Q[b] @ K[b]^T   (early-exit n-tiles >= first; scale in softmax)
    gemm_bt<2><<<dim3(S / 128, SK / 128, B), 256, 0, stream>>>(
        Qb, E, (long)S * E, Kb, E, (long)SK * E, nullptr, Sb, SK, (long)S * SK, E, seq, 2, 0);
    // softmax rows, in-place
    float scale = 1.0f / sqrtf((float)E);
    softmax_rows<<<dim3(S / 4, B), 256, 0, stream>>>(Sb, seq, scale);
    // out[b] = P[b] @ V[b]  (= P @ VT^T), K-loop bounded to ceil(first/64)*64
    gemm_bt<3><<<dim3(S / 128, E / 128, B), 256, 0, stream>>>(
        Sb, SK, (long)S * SK, VT, SK, (long)E * SK, nullptr, out, E, (long)S * E, 0, seq, 0, 1);
}

// Round 2
// 430.196 us; speedup vs baseline: 2.5231x; 2.5231x over previous
//
#include <hip/hip_runtime.h>
#include <hip/hip_bf16.h>
#include <cmath>

typedef __bf16 bf16x8 __attribute__((ext_vector_type(8)));
typedef __bf16 bf16x4 __attribute__((ext_vector_type(4)));
typedef float f32x4 __attribute__((ext_vector_type(4)));

#define GLOBAL_AS __attribute__((address_space(1)))
#define LDS_AS __attribute__((address_space(3)))

__device__ __forceinline__ void async_copy16(const void* g, void* l) {
    __builtin_amdgcn_global_load_lds((const GLOBAL_AS void*)g, (LDS_AS void*)l, 16, 0, 0);
}

// ---------------------------------------------------------------------------
// SEQ_idxes may be int64 or int32. As int32 words, int64 layout =
// [f0_lo, f0_hi(=0), ...]; int32 layout = [f0, s0(>=2049), ...]. seq[1]==0 <=> int64.
__device__ inline int get_first(const int* __restrict__ seq, int b) {
    int stride = (seq[1] == 0) ? 4 : 2;
    return seq[b * stride];
}

// ---------------------------------------------------------------------------
__global__ __launch_bounds__(256) void cast_f32_bf16(const float* __restrict__ in,
                                                     __bf16* __restrict__ out, int n4) {
    int i = blockIdx.x * 256 + threadIdx.x;
    if (i >= n4) return;
    float4 v = ((const float4*)in)[i];
    bf16x4 o;
    o[0] = (__bf16)v.x; o[1] = (__bf16)v.y; o[2] = (__bf16)v.z; o[3] = (__bf16)v.w;
    ((bf16x4*)out)[i] = o;
}

// 3 weight matrices in one dispatch (blockIdx.y selects)
__global__ __launch_bounds__(256) void cast3_f32_bf16(
    const float* __restrict__ a, const float* __restrict__ b, const float* __restrict__ c,
    __bf16* __restrict__ oa, __bf16* __restrict__ ob, __bf16* __restrict__ oc, int n4) {
    int i = blockIdx.x * 256 + threadIdx.x;
    if (i >= n4) return;
    const float* in = (blockIdx.y == 0) ? a : (blockIdx.y == 1) ? b : c;
    __bf16* out = (blockIdx.y == 0) ? oa : (blockIdx.y == 1) ? ob : oc;
    float4 v = ((const float4*)in)[i];
    bf16x4 o;
    o[0] = (__bf16)v.x; o[1] = (__bf16)v.y; o[2] = (__bf16)v.z; o[3] = (__bf16)v.w;
    ((bf16x4*)out)[i] = o;
}

__global__ __launch_bounds__(256) void zero_f32(float* __restrict__ p, int n4) {
    int i = blockIdx.x * 256 + threadIdx.x;
    if (i < n4) ((f32x4*)p)[i] = f32x4{0.f, 0.f, 0.f, 0.f};
}

// ---------------------------------------------------------------------------
// gemm_bt: C[m][n] = sum_k A[m][k] * Bt[n][k]  (+ bias[n])
// A: row-major M x K (lda), Bt: row-major N x K (ldb). 128x128 tile, BK=64,
// 256 threads = 4 waves (2x2), wave = 4x4 of 16x16x32 bf16 MFMA.
// Staging: global_load_lds width=16; LDS layout XOR-swizzled via the GLOBAL
// source index (dest is wave-uniform base + lane*16, so no padding possible):
//   LDS slot s (16B) holds global chunk (row=s>>3, c8=(s&7)^(row&7)).
// Frag read chunk for (row R, pos p) lives at byte R*128 + ((p^(R&7))*16)
//   -> 16 lanes (R&7 covers 0..7 twice) spread over all 8 positions: 2-way only.
// EPI: 0 = bf16 + bias; 1 = bf16 TRANSPOSED (C[n][m]) + bias;
//      2 = p=exp2(acc*cs) masked to [1,first), bf16 store + atomic rowsum;
//      3 = fp32 store scaled by 1/rowsum[row].
// exit_mode: 0 none, 1 skip if m0>=first, 2 skip if n0>=first.
// k_mode: 0 K=Kfix, 1 K=roundup64(first).
template <int EPI>
__global__ __launch_bounds__(256) void gemm_bt(
    const __bf16* __restrict__ A, int lda, long strideA,
    const __bf16* __restrict__ B, int ldb, long strideB,
    const float* __restrict__ bias,
    void* __restrict__ Cv, int ldc, long strideC,
    int Kfix, const int* __restrict__ seq, int exit_mode, int k_mode,
    float cs, float* __restrict__ rowsum) {
    int z = blockIdx.z;
    int m0 = blockIdx.x * 128, n0 = blockIdx.y * 128;
    int first = seq ? get_first(seq, z) : 0;
    if (exit_mode == 1 && m0 >= first) return;
    if (exit_mode == 2 && n0 >= first) return;
    int K = k_mode ? ((first + 63) & ~63) : Kfix;

    __shared__ char As[16384];
    __shared__ char Bs[16384];

    int tid = threadIdx.x;
    int lane = tid & 63, wid = tid >> 6;
    int waveM = (wid & 1) << 6, waveN = (wid >> 1) << 6;
    int quad = lane >> 4, l16 = lane & 15;

    // staging source: row r0 (+32 per round), swizzled 16B-chunk c8 (round-invariant)
    int r0 = tid >> 3;
    int c8 = (tid & 7) ^ (r0 & 7);
    const __bf16* Ag = A + (long)z * strideA + (long)(m0 + r0) * lda + c8 * 8;
    const __bf16* Bg = B + (long)z * strideB + (long)(n0 + r0) * ldb + c8 * 8;

    f32x4 acc[4][4] = {};
    int xorv = (l16 & 7) << 4;  // frag-read swizzle (byte units)

    for (int k0 = 0; k0 < K; k0 += 64) {
        __syncthreads();  // prior iter's ds_reads done before overwrite
#pragma unroll
        for (int r = 0; r < 4; ++r) {
            async_copy16(Ag + (long)(r * 32) * lda + k0, As + (tid + r * 256) * 16);
            async_copy16(Bg + (long)(r * 32) * ldb + k0, Bs + (tid + r * 256) * 16);
        }
        __syncthreads();  // drains vmcnt (compiler emits waitcnt before barrier)
#pragma unroll
        for (int s = 0; s < 2; ++s) {
            bf16x8 af[4], bfr[4];
#pragma unroll
            for (int i = 0; i < 4; ++i) {
                int chunk = (((s << 2) + quad) << 4) ^ xorv;
                af[i]  = *(const bf16x8*)(As + (waveM + i * 16 + l16) * 128 + chunk);
                bfr[i] = *(const bf16x8*)(Bs + (waveN + i * 16 + l16) * 128 + chunk);
            }
#pragma unroll
            for (int i = 0; i < 4; ++i)
#pragma unroll
                for (int j = 0; j < 4; ++j)
                    acc[i][j] = __builtin_amdgcn_mfma_f32_16x16x32_bf16(af[i], bfr[j], acc[i][j], 0, 0, 0);
        }
    }

    // C/D frag: col = l16 (n), row = quad*4 + reg (m). [m89-verified]
    if (EPI == 0) {
        __bf16* C = (__bf16*)Cv + (long)z * strideC;
#pragma unroll
        for (int i = 0; i < 4; ++i) {
            int rowb = m0 + waveM + i * 16 + quad * 4;
#pragma unroll
            for (int j = 0; j < 4; ++j) {
                int col = n0 + waveN + j * 16 + l16;
                float bv_ = bias[col];
#pragma unroll
                for (int r = 0; r < 4; ++r)
                    C[(long)(rowb + r) * ldc + col] = (__bf16)(acc[i][j][r] + bv_);
            }
        }
    } else if (EPI == 1) {
        __bf16* C = (__bf16*)Cv + (long)z * strideC;
#pragma unroll
        for (int i = 0; i < 4; ++i) {
            int rowb = m0 + waveM + i * 16 + quad * 4;
#pragma unroll
            for (int j = 0; j < 4; ++j) {
                int col = n0 + waveN + j * 16 + l16;
                float bv_ = bias[col];
                bf16x4 o;
#pragma unroll
                for (int r = 0; r < 4; ++r) o[r] = (__bf16)(acc[i][j][r] + bv_);
                *(bf16x4*)&C[(long)col * ldc + rowb] = o;  // rowb%4==0 -> 8B aligned
            }
        }
    } else if (EPI == 2) {
        __bf16* C = (__bf16*)Cv + (long)z * strideC;
        float* rs = rowsum + (long)z * 4096;
#pragma unroll
        for (int i = 0; i < 4; ++i) {
            int rowb = m0 + waveM + i * 16 + quad * 4;
            float sum[4] = {0.f, 0.f, 0.f, 0.f};
#pragma unroll
            for (int j = 0; j < 4; ++j) {
                int col = n0 + waveN + j * 16 + l16;
                bool valid = (col >= 1) && (col < first);
#pragma unroll
                for (int r = 0; r < 4; ++r) {
                    float e = valid ? exp2f(acc[i][j][r] * cs) : 0.0f;
                    __bf16 pb = (__bf16)e;
                    C[(long)(rowb + r) * ldc + col] = pb;
                    sum[r] += (float)pb;  // sum the bf16-rounded value (consistent w/ PV)
                }
            }
#pragma unroll
            for (int r = 0; r < 4; ++r) {
                float v = sum[r];
                v += __shfl_xor(v, 8); v += __shfl_xor(v, 4);
                v += __shfl_xor(v, 2); v += __shfl_xor(v, 1);
                if (l16 == 0) atomicAdd(&rs[rowb + r], v);
            }
        }
    } else {
        float* C = (float*)Cv + (long)z * strideC;
        const float* rs = rowsum + (long)z * 4096;
#pragma unroll
        for (int i = 0; i < 4; ++i) {
            int rowb = m0 + waveM + i * 16 + quad * 4;
            float inv[4];
#pragma unroll
            for (int r = 0; r < 4; ++r) inv[r] = 1.0f / rs[rowb + r];
#pragma unroll
            for (int j = 0; j < 4; ++j) {
                int col = n0 + waveN + j * 16 + l16;
#pragma unroll
                for (int r = 0; r < 4; ++r)
                    C[(long)(rowb + r) * ldc + col] = acc[i][j][r] * inv[r];
            }
        }
    }
}

// ---------------------------------------------------------------------------
extern "C" void kernel_launch(void* const* d_in, const int* in_sizes, int n_in,
                              void* d_out, int out_size, void* d_ws, size_t ws_size,
                              hipStream_t stream) {
    const int B = 8, S = 4096, E = 768, SK = 2048;
    const float* ebd  = (const float*)d_in[0];
    const int*   seq  = (const int*)d_in[1];
    const float* Wq_w = (const float*)d_in[2];
    const float* Wq_b = (const float*)d_in[3];
    const float* Wk_w = (const float*)d_in[4];
    const float* Wk_b = (const float*)d_in[5];
    const float* Wv_w = (const float*)d_in[6];
    const float* Wv_b = (const float*)d_in[7];
    float* out = (float*)d_out;

    char* p = (char*)d_ws;
    __bf16* ebd_bf = (__bf16*)p; p += (size_t)B * S * E * 2;   // 50.3 MB
    __bf16* wq = (__bf16*)p;     p += (size_t)E * E * 2;
    __bf16* wk = (__bf16*)p;     p += (size_t)E * E * 2;
    __bf16* wv = (__bf16*)p;     p += (size_t)E * E * 2;
    __bf16* Qb = (__bf16*)p;     p += (size_t)B * S * E * 2;   // 50.3 MB
    __bf16* Kb = (__bf16*)p;     p += (size_t)B * SK * E * 2;  // 25.2 MB
    __bf16* VT = (__bf16*)p;     p += (size_t)B * E * SK * 2;  // 25.2 MB  V^T: [b][e][k]
    __bf16* Pb = (__bf16*)p;     p += (size_t)B * S * SK * 2;  // 134.2 MB exp-scores
    float* rowsum = (float*)p;   p += (size_t)B * S * 4;       // 128 KB

    zero_f32<<<B * S / 4 / 256, 256, 0, stream>>>(rowsum, B * S / 4);
    cast_f32_bf16<<<(B * S * E / 4 + 255) / 256, 256, 0, stream>>>(ebd, ebd_bf, B * S * E / 4);
    cast3_f32_bf16<<<dim3((E * E / 4 + 255) / 256, 3), 256, 0, stream>>>(
        Wq_w, Wk_w, Wv_w, wq, wk, wv, E * E / 4);

    float cs = (1.0f / sqrtf((float)E)) * 1.44269504088896f;  // scale * log2(e)

    // Q = ebd @ Wq^T + bq  (M = B*S as one GEMM)
    gemm_bt<0><<<dim3(B * S / 128, E / 128, 1), 256, 0, stream>>>(
        ebd_bf, E, 0, wq, E, 0, Wq_b, Qb, E, 0, E, nullptr, 0, 0, 0.f, nullptr);
    // K[b] = ebd[b,0:2048] @ Wk^T + bk  (skip m-tiles >= first)
    gemm_bt<0><<<dim3(SK / 128, E / 128, B), 256, 0, stream>>>(
        ebd_bf, E, (long)S * E, wk, E, 0, Wk_b, Kb, E, (long)SK * E, E, seq, 1, 0, 0.f, nullptr);
    // VT[b] = (ebd[b,0:2048] @ Wv^T + bv)^T
    gemm_bt<1><<<dim3(SK / 128, E / 128, B), 256, 0, stream>>>(
        ebd_bf, E, (long)S * E, wv, E, 0, Wv_b, VT, SK, (long)E * SK, E, seq, 1, 0, 0.f, nullptr);
    // P[b] = exp(Q K^T * scale) masked to [1,first), + rowsum atomics
    gemm_bt<2><<<dim3(S / 128, SK / 128, B), 256, 0, stream>>>(
        Qb, E, (long)S * E, Kb, E, (long)SK * E, nullptr, Pb, SK, (long)S * SK, E, seq, 2, 0, cs, rowsum);
    // out[b] = (P[b] @ V[b]) / rowsum  (K bounded to roundup64(first))
    gemm_bt<3><<<dim3(S / 128, E / 128, B), 256, 0, stream>>>(
        Pb, SK, (long)S * SK, VT, SK, (long)E * SK, nullptr, out, E, (long)S * E, 0, seq, 0, 1, 0.f, rowsum);
}